// Round 3
// baseline (116.829 us; speedup 1.0000x reference)
//
#include <hip/hip_runtime.h>

// ---------------------------------------------------------------------------
// SgpiSTFT: Hermitian iFFT (as GEMM vs fixed cos/sin matrix) + window + 4-tap
// overlap-add + flip/transpose, fused.
//
//   y[n,t] = Re(c0) + 2*sum_{k=1..255}( Re_k cos(2pi n k/512) + Im_k sin(...) )
//   out[b, t*256 + (255-j)] = 256*( y[256+j,t]  *win[768+j]
//                                  + y[j,  t-1] *win[512+j]
//                                  + y[256+j,t-2]*win[256+j]
//                                  + y[j,  t-3] *win[j] )
// Symmetry: y[256+j] flips sign of odd-k terms -> accumulate even-k (E) and
// odd-k (O) halves; Y=E+O, Yh=E-O.
//
// Round-3 structure (STILL UNMEASURED — 3rd resubmit, broker at capacity):
// same validated M layout / MFMA operand order / OLA epilogue as round 2,
// but the t-tile is widened 32 -> 64 columns:
//   - 8 MFMAs per s-step per wave against the same 2 M prefetch loads
//     (2x compute per L2 load, hides ~200cy L2 latency)
//   - per-block M re-read amortized over 2x the useful columns
//   - halo waste 28/32 -> 60/64; grid 1144 -> 536 blocks (~1.05x resident)
// LDS 64 KiB (2 blocks/CU), __launch_bounds__(512,4) pins 4 waves/SIMD.
// Static audit r2: coverage/masking, 16B alignment, VGPR budget (~110<128),
// epilogue edge lanes — all consistent.
// ---------------------------------------------------------------------------

typedef __attribute__((ext_vector_type(8))) short short8;
typedef __attribute__((ext_vector_type(8))) __bf16 bf16x8;
typedef __attribute__((ext_vector_type(4))) float floatx4;

__device__ inline short f2bf(float f) {
  unsigned u = __builtin_bit_cast(unsigned, f);
  u = (u + 0x7fffu + ((u >> 16) & 1u)) >> 16;
  return (short)(unsigned short)u;
}

#define PI_OVER_256 0.01227184630308513f

// M matrix in MFMA fragment order, identical to rounds 1-2 (validated):
//   frag idx = (Jtile*16 + s)*64 + lane ; lane holds row j = Jtile*16+(lane&15),
//   kappa = s*32 + (lane>>4)*8 + e, e=0..7 (one short8 per lane).
//   kappa < 256: gk = 2*kappa (even);  kappa >= 256: gk = 2*(kappa-256)+1 (odd)
//   M[j][gk] = (gk==0) ? 1 : (gk<256 ? 2cos(2pi j gk/512) : 2sin(2pi j (gk-256)/512))
__global__ void build_m(short* __restrict__ M) {
  int idx = blockIdx.x * blockDim.x + threadIdx.x;  // [0, 16*16*64)
  int ntile = idx >> 10;
  int s = (idx >> 6) & 15;
  int lane = idx & 63;
  int n = ntile * 16 + (lane & 15);
  int kb = lane >> 4;
  short8 v;
#pragma unroll
  for (int e = 0; e < 8; e++) {
    int kap = s * 32 + kb * 8 + e;
    int gk = 2 * (kap & 255) + (kap >> 8);
    float val;
    if (gk == 0) {
      val = 1.0f;
    } else if (gk < 256) {
      int m = (n * gk) & 511;
      val = 2.0f * __cosf((float)m * PI_OVER_256);
    } else {
      int m = (n * (gk - 256)) & 511;
      val = 2.0f * __sinf((float)m * PI_OVER_256);
    }
    v[e] = f2bf(val);
  }
  ((short8*)M)[idx] = v;
}

// Block: batch b, X columns [c0, c0+64), c0 = 60*tile - 4 (halo 4, 16B-aligned
// global loads). Outputs local L in [4,64) -> t = c0+L, masked to t <= 3998.
// 512 threads = 8 waves; wave w owns j-tiles {2w, 2w+1} (j rows 32w..32w+31)
// for ALL 64 t-columns.
__global__ __launch_bounds__(512, 4) void gemm_ola(
    const float* __restrict__ in, const float* __restrict__ win,
    const short* __restrict__ M, float* __restrict__ out) {
  // X tile, bf16, column-major [col][kappa], kappa groups of 8 XOR-swizzled by
  // (col&7) -> conflict-tolerable b128 reads/writes.
  __shared__ short ldsX[64 * 512];  // 64 KiB

  const int tid = threadIdx.x;
  const int b = blockIdx.y;
  const int tile = blockIdx.x;
  const int c0 = 60 * tile - 4;

  // ---- stage X: dwordx4 global loads + register transpose -> bf16 LDS ----
  // 2 passes: pass covers kappa [pass*256, pass*256+256), 16 col-groups x 4.
  {
    const int cbase = 4 * (tid & 15);    // 4 consecutive cols
    const int gc = c0 + cbase;
    const bool ok = (gc >= 0 && gc <= 3996);
    const float* src = in + (size_t)b * 2056000 + gc;
#pragma unroll
    for (int pass = 0; pass < 2; pass++) {
      const int kap0 = (tid >> 4) * 8 + pass * 256;  // 8 consecutive kappa
      floatx4 f[8];
      if (ok) {
#pragma unroll
        for (int j = 0; j < 8; j++) {
          int kap = kap0 + j;
          int gk = 2 * (kap & 255) + (kap >> 8);
          int row = (gk < 256) ? gk : gk + 1;  // imag rows start at 257
          f[j] = *(const floatx4*)(src + (size_t)row * 4000);
        }
      } else {
#pragma unroll
        for (int j = 0; j < 8; j++) f[j] = floatx4{0.f, 0.f, 0.f, 0.f};
      }
      const int g = kap0 >> 3;  // kappa-group, 8-aligned
#pragma unroll
      for (int cc = 0; cc < 4; cc++) {
        short8 v;
#pragma unroll
        for (int j = 0; j < 8; j++) v[j] = f2bf(f[j][cc]);
        const int col = cbase + cc;
        *(short8*)&ldsX[col * 512 + ((g ^ (col & 7)) << 3)] = v;
      }
    }
  }
  __syncthreads();

  const int w = tid >> 6;
  const int lane = tid & 63;
  const int c = lane & 15;   // MFMA spatial index within 16-tile
  const int kb = lane >> 4;  // k-block; also C row-group rg
  const int rg = kb;

  // acc[q][jt]: q = t-tile (rows of C, 4 tiles = 64 cols), jt = j-tile
  floatx4 accE[4][2] = {};
  floatx4 accO[4][2] = {};

  const short8* Mf = (const short8*)M;
  const int J0 = 2 * w, J1 = 2 * w + 1;

  bf16x8 cb0 = __builtin_bit_cast(bf16x8, Mf[(J0 * 16 + 0) * 64 + lane]);
  bf16x8 cb1 = __builtin_bit_cast(bf16x8, Mf[(J1 * 16 + 0) * 64 + lane]);

#pragma unroll
  for (int s = 0; s < 16; s++) {
    // prefetch next-s M fragments (L2) before touching this step's MFMAs
    bf16x8 nb0, nb1;
    if (s < 15) {
      nb0 = __builtin_bit_cast(bf16x8, Mf[(J0 * 16 + s + 1) * 64 + lane]);
      nb1 = __builtin_bit_cast(bf16x8, Mf[(J1 * 16 + s + 1) * 64 + lane]);
    }
    // A fragments (X) from LDS: lane m = t-col; 4 t-tiles
    const int g = 4 * s + kb;
    bf16x8 a[4];
#pragma unroll
    for (int q = 0; q < 4; q++) {
      const int col = 16 * q + c;
      a[q] = __builtin_bit_cast(
          bf16x8, *(const short8*)&ldsX[col * 512 + ((g ^ (col & 7)) << 3)]);
    }
    if (s < 8) {
#pragma unroll
      for (int q = 0; q < 4; q++) {
        accE[q][0] = __builtin_amdgcn_mfma_f32_16x16x32_bf16(a[q], cb0, accE[q][0], 0, 0, 0);
        accE[q][1] = __builtin_amdgcn_mfma_f32_16x16x32_bf16(a[q], cb1, accE[q][1], 0, 0, 0);
      }
    } else {
#pragma unroll
      for (int q = 0; q < 4; q++) {
        accO[q][0] = __builtin_amdgcn_mfma_f32_16x16x32_bf16(a[q], cb0, accO[q][0], 0, 0, 0);
        accO[q][1] = __builtin_amdgcn_mfma_f32_16x16x32_bf16(a[q], cb1, accO[q][1], 0, 0, 0);
      }
    }
    if (s < 15) { cb0 = nb0; cb1 = nb1; }
  }

  // ---- OLA epilogue ----
  // C layout: col (lane&15) = j within j-tile; row (rg*4+p) = local t offset.
  // Tap t-d = reg p-d; p-d<0 pulls reg p-d+4 from the row-group below
  // (lane-16, same q-tile) or, for rg==0, from rg=3 of tile q-1 (lane+48).
  // q==0 && rg==0 edge rows are L<4 -> masked.
#pragma unroll
  for (int jt = 0; jt < 2; jt++) {
    const int J = 2 * w + jt;
    const int j = 16 * J + c;
    const float wv0 = 256.0f * win[768 + j];
    const float wv1 = 256.0f * win[512 + j];
    const float wv2 = 256.0f * win[256 + j];
    const float wv3 = 256.0f * win[j];

    floatx4 Y[4], Yh[4];
#pragma unroll
    for (int q = 0; q < 4; q++) {
      Y[q] = accE[q][jt] + accO[q][jt];
      Yh[q] = accE[q][jt] - accO[q][jt];
    }

#pragma unroll
    for (int q = 0; q < 4; q++) {
      const int qm = (q > 0) ? q - 1 : 0;  // q==0 edge is masked (L<4)
      float yb[4], yhb[4];
#pragma unroll
      for (int p = 1; p < 4; p++) {
        float ia = __shfl(Y[q][p], lane - 16, 64);
        float pa = __shfl(Y[qm][p], lane + 48, 64);
        yb[p] = (rg > 0) ? ia : pa;
      }
#pragma unroll
      for (int p = 2; p < 4; p++) {
        float ia = __shfl(Yh[q][p], lane - 16, 64);
        float pa = __shfl(Yh[qm][p], lane + 48, 64);
        yhb[p] = (rg > 0) ? ia : pa;
      }
      floatx4 v;
#pragma unroll
      for (int p = 0; p < 4; p++) {
        float t1 = (p >= 1) ? Y[q][p - 1] : yb[3];
        float t2 = (p >= 2) ? Yh[q][p - 2] : yhb[p + 2];
        float t3 = (p >= 3) ? Y[q][p - 3] : yb[p + 1];
        v[p] = wv0 * Yh[q][p] + wv1 * t1 + wv2 * t2 + wv3 * t3;
      }
#pragma unroll
      for (int p = 0; p < 4; p++) {
        const int L = 16 * q + 4 * rg + p;
        const int t = c0 + L;
        if (L >= 4 && t <= 3998) {
          out[((size_t)b * 3999 + t) * 256 + (255 - j)] = v[p];
        }
      }
    }
  }
}

extern "C" void kernel_launch(void* const* d_in, const int* in_sizes, int n_in,
                              void* d_out, int out_size, void* d_ws, size_t ws_size,
                              hipStream_t stream) {
  const float* in = (const float*)d_in[0];   // (8, 514, 4000) fp32
  const float* win = (const float*)d_in[1];  // (1024,) fp32
  float* out = (float*)d_out;                // (8, 3999*256) fp32
  short* M = (short*)d_ws;                   // 256 KiB bf16 coefficient matrix

  hipLaunchKernelGGL(build_m, dim3(64), dim3(256), 0, stream, M);
  hipLaunchKernelGGL(gemm_ola, dim3(67, 8), dim3(512), 0, stream, in, win, M, out);
}